// Round 1
// baseline (2218.421 us; speedup 1.0000x reference)
//
#include <hip/hip_runtime.h>
#include <stdint.h>

// Problem constants (verified against in_sizes at launch)
// x[N,128] f32, edge_index[2,E] int32/64, ew[E] f32, W1[64,128], b1[64], W2[128,64], b2[128]
#define FIN 128
#define FHID 64
#define CHUNK 2048

// ---------- dtype detection: int64 edge_index has odd 32-bit words == 0 ----------
__global__ void k_detect(const uint32_t* __restrict__ ei, int* __restrict__ flag) {
    if (blockIdx.x == 0 && threadIdx.x == 0) {
        uint32_t o = 0;
        #pragma unroll
        for (int i = 1; i < 16; i += 2) o |= ei[i];
        *flag = (o == 0) ? 1 : 0;
    }
}

__device__ __forceinline__ int edge_at(const void* ei, long long idx, int is64) {
    if (is64) return (int)((const long long*)ei)[idx];
    return ((const int*)ei)[idx];
}

// ---------- degree (weighted) + count histogram ----------
__global__ __launch_bounds__(256) void k_deg(const void* __restrict__ ei, const float* __restrict__ w,
                                             float* __restrict__ wdeg, int* __restrict__ cnt,
                                             const int* __restrict__ flag, int E) {
    int e = blockIdx.x * 256 + threadIdx.x;
    if (e >= E) return;
    int is64 = *flag;
    int c = edge_at(ei, (long long)E + e, is64);
    atomicAdd(&wdeg[c], w[e]);
    atomicAdd(&cnt[c], 1);
}

// ---------- deg -> deg^-1/2 in place ----------
__global__ __launch_bounds__(256) void k_dis(float* wdeg, int N) {
    int i = blockIdx.x * 256 + threadIdx.x;
    if (i < N) {
        float d = wdeg[i];
        wdeg[i] = (d > 0.f) ? rsqrtf(d) : 0.f;
    }
}

// ---------- exclusive scan of cnt -> row_start (3-kernel hierarchical) ----------
__global__ __launch_bounds__(256) void k_scan_part(const int* __restrict__ cnt, int* __restrict__ partial, int N) {
    __shared__ int sdata[256];
    int b = blockIdx.x, t = threadIdx.x;
    int base = b * CHUNK;
    int sum = 0;
    #pragma unroll
    for (int q = 0; q < CHUNK / 256; ++q) {
        int idx = base + q * 256 + t;
        if (idx < N) sum += cnt[idx];
    }
    sdata[t] = sum; __syncthreads();
    for (int off = 128; off > 0; off >>= 1) {
        if (t < off) sdata[t] += sdata[t + off];
        __syncthreads();
    }
    if (t == 0) partial[b] = sdata[0];
}

__global__ void k_scan_top(int* partial, int nparts, int* row_start, int N) {
    if (blockIdx.x == 0 && threadIdx.x == 0) {
        int run = 0;
        for (int i = 0; i < nparts; ++i) { int v = partial[i]; partial[i] = run; run += v; }
        row_start[N] = run;   // == E
    }
}

__global__ __launch_bounds__(256) void k_scan_chunk(const int* __restrict__ cnt, const int* __restrict__ partial,
                                                    int* __restrict__ row_start, int N) {
    __shared__ int tsum[256];
    __shared__ int toff[256];
    int b = blockIdx.x, t = threadIdx.x;
    int base = b * CHUNK + t * 8;
    int v[8]; int s = 0;
    #pragma unroll
    for (int q = 0; q < 8; ++q) {
        int idx = base + q;
        v[q] = (idx < N) ? cnt[idx] : 0;
        s += v[q];
    }
    tsum[t] = s; __syncthreads();
    if (t == 0) {
        int run = partial[b];
        for (int i = 0; i < 256; ++i) { int x = tsum[i]; toff[i] = run; run += x; }
    }
    __syncthreads();
    int ex = toff[t];
    #pragma unroll
    for (int q = 0; q < 8; ++q) {
        int idx = base + q;
        if (idx < N) row_start[idx] = ex;
        ex += v[q];
    }
}

// ---------- CSR fill: csr[pos] = {src, norm} grouped by dst ----------
__global__ __launch_bounds__(256) void k_fill(const void* __restrict__ ei, const float* __restrict__ w,
                                              const float* __restrict__ dis, const int* __restrict__ row_start,
                                              int* __restrict__ cursor, int2* __restrict__ csr,
                                              const int* __restrict__ flag, int E) {
    int e = blockIdx.x * 256 + threadIdx.x;
    if (e >= E) return;
    int is64 = *flag;
    int r = edge_at(ei, e, is64);
    int c = edge_at(ei, (long long)E + e, is64);
    float nm = dis[r] * w[e] * dis[c];
    int pos = row_start[c] + atomicAdd(&cursor[c], 1);
    csr[pos] = make_int2(r, __float_as_int(nm));
}

// ---------- GEMM1: h1lin[N,64] = x[N,128] @ W1[64,128]^T ----------
__global__ __launch_bounds__(256) void k_gemm1(const float* __restrict__ x, const float* __restrict__ W1,
                                               float* __restrict__ h1lin, int N) {
    __shared__ float Wt[FIN * FHID];    // Wt[k*64+j] = W1[j*128+k]  (32 KB)
    __shared__ float xt[32 * FIN];      // 16 KB
    int t = threadIdx.x;
    for (int i = t; i < FHID * FIN; i += 256) {
        int j = i >> 7, k = i & 127;
        Wt[k * FHID + j] = W1[i];
    }
    int r0 = blockIdx.x * 32;
    const float4* xg = (const float4*)(x + (size_t)r0 * FIN);
    float4* xt4 = (float4*)xt;
    #pragma unroll
    for (int q = 0; q < 4; ++q) {
        int i = t + q * 256;            // 1024 float4 total, 32 per row
        if (r0 + (i >> 5) < N) xt4[i] = xg[i];
    }
    __syncthreads();
    int j = t & 63, rg = t >> 6;        // rg uniform per wave
    float acc[8];
    #pragma unroll
    for (int r = 0; r < 8; ++r) acc[r] = 0.f;
    for (int kk = 0; kk < FIN; kk += 4) {
        float w0 = Wt[(kk + 0) * FHID + j];
        float w1 = Wt[(kk + 1) * FHID + j];
        float w2 = Wt[(kk + 2) * FHID + j];
        float w3 = Wt[(kk + 3) * FHID + j];
        #pragma unroll
        for (int r = 0; r < 8; ++r) {
            float4 xv = xt4[(rg * 8 + r) * 32 + (kk >> 2)];
            acc[r] += xv.x * w0 + xv.y * w1 + xv.z * w2 + xv.w * w3;
        }
    }
    #pragma unroll
    for (int r = 0; r < 8; ++r) {
        int row = r0 + rg * 8 + r;
        if (row < N) h1lin[(size_t)row * FHID + j] = acc[r];
    }
}

// ---------- aggregation layer1: h1 = relu(sum norm*h1lin[src] + b1), F=64 ----------
__global__ __launch_bounds__(256) void k_agg1(const int2* __restrict__ csr, const int* __restrict__ row_start,
                                              const float* __restrict__ h1lin, const float* __restrict__ b1,
                                              float* __restrict__ h1, int N) {
    int wid = threadIdx.x >> 6, lane = threadIdx.x & 63;
    int node = blockIdx.x * 4 + wid;
    if (node >= N) return;
    int s = row_start[node], epos = row_start[node + 1];
    float acc = 0.f;
    for (int base = s; base < epos; base += 64) {
        int m = epos - base; if (m > 64) m = 64;
        int2 ent = (lane < m) ? csr[base + lane] : make_int2(0, 0);
        for (int i = 0; i < m; ++i) {
            int src = __shfl(ent.x, i);
            float nm = __shfl(__int_as_float(ent.y), i);
            acc += nm * h1lin[(size_t)src * FHID + lane];
        }
    }
    h1[(size_t)node * FHID + lane] = fmaxf(acc + b1[lane], 0.f);
}

// ---------- aggregation layer2 (pre-transform): aggv = sum norm*h1[src], F=64 ----------
__global__ __launch_bounds__(256) void k_agg2(const int2* __restrict__ csr, const int* __restrict__ row_start,
                                              const float* __restrict__ h1, float* __restrict__ aggv, int N) {
    int wid = threadIdx.x >> 6, lane = threadIdx.x & 63;
    int node = blockIdx.x * 4 + wid;
    if (node >= N) return;
    int s = row_start[node], epos = row_start[node + 1];
    float acc = 0.f;
    for (int base = s; base < epos; base += 64) {
        int m = epos - base; if (m > 64) m = 64;
        int2 ent = (lane < m) ? csr[base + lane] : make_int2(0, 0);
        for (int i = 0; i < m; ++i) {
            int src = __shfl(ent.x, i);
            float nm = __shfl(__int_as_float(ent.y), i);
            acc += nm * h1[(size_t)src * FHID + lane];
        }
    }
    aggv[(size_t)node * FHID + lane] = acc;
}

// ---------- GEMM2 fused: out[N,128] = relu(aggv[N,64] @ W2[128,64]^T + b2) ----------
__global__ __launch_bounds__(256) void k_gemm2(const float* __restrict__ A, const float* __restrict__ W2,
                                               const float* __restrict__ b2, float* __restrict__ out, int N) {
    __shared__ float Wt[FHID * FIN];    // Wt[k*128+j] = W2[j*64+k]  (32 KB)
    __shared__ float xt[16 * FHID];     // 4 KB
    int t = threadIdx.x;
    for (int i = t; i < FIN * FHID; i += 256) {
        int j = i >> 6, k = i & 63;
        Wt[k * FIN + j] = W2[i];
    }
    int r0 = blockIdx.x * 16;
    const float4* xg = (const float4*)(A + (size_t)r0 * FHID);
    float4* xt4 = (float4*)xt;
    {
        int i = t;                      // 256 float4 total, 16 per row
        if (r0 + (i >> 4) < N) xt4[i] = xg[i];
    }
    __syncthreads();
    int j = t & 127, rg = t >> 7;       // rg uniform per wave
    float acc[8];
    #pragma unroll
    for (int r = 0; r < 8; ++r) acc[r] = 0.f;
    for (int kk = 0; kk < FHID; kk += 4) {
        float w0 = Wt[(kk + 0) * FIN + j];
        float w1 = Wt[(kk + 1) * FIN + j];
        float w2 = Wt[(kk + 2) * FIN + j];
        float w3 = Wt[(kk + 3) * FIN + j];
        #pragma unroll
        for (int r = 0; r < 8; ++r) {
            float4 xv = xt4[(rg * 8 + r) * 16 + (kk >> 2)];
            acc[r] += xv.x * w0 + xv.y * w1 + xv.z * w2 + xv.w * w3;
        }
    }
    float bj = b2[j];
    #pragma unroll
    for (int r = 0; r < 8; ++r) {
        int row = r0 + rg * 8 + r;
        if (row < N) out[(size_t)row * FIN + j] = fmaxf(acc[r] + bj, 0.f);
    }
}

extern "C" void kernel_launch(void* const* d_in, const int* in_sizes, int n_in,
                              void* d_out, int out_size, void* d_ws, size_t ws_size,
                              hipStream_t stream) {
    const float* x  = (const float*)d_in[0];
    const void*  ei = d_in[1];
    const float* w  = (const float*)d_in[2];
    const float* W1 = (const float*)d_in[3];
    const float* b1 = (const float*)d_in[4];
    const float* W2 = (const float*)d_in[5];
    const float* b2 = (const float*)d_in[6];
    float* out = (float*)d_out;
    int N = in_sizes[0] / FIN;
    int E = in_sizes[2];

    char* ws = (char*)d_ws;
    size_t off = 0;
    auto alloc = [&](size_t b) { size_t o = off; off = (off + b + 255) & ~255ULL; return o; };
    int*   flag      = (int*)(ws + alloc(4));
    float* wdeg      = (float*)(ws + alloc((size_t)N * 4));       // becomes dis
    int*   cnt       = (int*)(ws + alloc((size_t)N * 4));
    int*   cursor    = (int*)(ws + alloc((size_t)N * 4));
    int*   row_start = (int*)(ws + alloc((size_t)(N + 1) * 4));
    int*   partial   = (int*)(ws + alloc(4096));
    int2*  csr       = (int2*)(ws + alloc((size_t)E * 8));
    float* h1        = (float*)(ws + alloc((size_t)N * FHID * 4));
    float* scratch   = (float*)(ws + alloc((size_t)N * FHID * 4)); // h1lin, then aggv

    hipMemsetAsync(wdeg, 0, (size_t)N * 4, stream);
    hipMemsetAsync(cnt, 0, (size_t)N * 4, stream);
    hipMemsetAsync(cursor, 0, (size_t)N * 4, stream);

    k_detect<<<1, 64, 0, stream>>>((const uint32_t*)ei, flag);

    int eb = (E + 255) / 256;
    k_deg<<<eb, 256, 0, stream>>>(ei, w, wdeg, cnt, flag, E);
    k_dis<<<(N + 255) / 256, 256, 0, stream>>>(wdeg, N);

    int nparts = (N + CHUNK - 1) / CHUNK;
    k_scan_part<<<nparts, 256, 0, stream>>>(cnt, partial, N);
    k_scan_top<<<1, 64, 0, stream>>>(partial, nparts, row_start, N);
    k_scan_chunk<<<nparts, 256, 0, stream>>>(cnt, partial, row_start, N);

    k_fill<<<eb, 256, 0, stream>>>(ei, w, wdeg, row_start, cursor, csr, flag, E);

    k_gemm1<<<(N + 31) / 32, 256, 0, stream>>>(x, W1, scratch, N);
    k_agg1<<<(N + 3) / 4, 256, 0, stream>>>(csr, row_start, scratch, b1, h1, N);
    k_agg2<<<(N + 3) / 4, 256, 0, stream>>>(csr, row_start, h1, scratch, N);
    k_gemm2<<<(N + 15) / 16, 256, 0, stream>>>(scratch, W2, b2, out, N);
}

// Round 2
// 1917.157 us; speedup vs baseline: 1.1571x; 1.1571x over previous
//
#include <hip/hip_runtime.h>
#include <stdint.h>

// x[N,128] f32, edge_index[2,E] int32/64, ew[E] f32, W1[64,128], b1[64], W2[128,64], b2[128]
#define FIN 128
#define FHID 64
#define CHUNK 2048
#define FIX_SCALE 16777216.0f   // 2^24
#define FIX_INV   (1.0f / 16777216.0f)

// ---------- dtype detection: int64 edge_index has odd 32-bit words == 0 ----------
__global__ void k_detect(const uint32_t* __restrict__ ei, int* __restrict__ flag) {
    if (blockIdx.x == 0 && threadIdx.x == 0) {
        uint32_t o = 0;
        #pragma unroll
        for (int i = 1; i < 16; i += 2) o |= ei[i];
        *flag = (o == 0) ? 1 : 0;
    }
}

__device__ __forceinline__ int edge_at(const void* ei, long long idx, int is64) {
    if (is64) return (int)((const long long*)ei)[idx];
    return ((const int*)ei)[idx];
}

// ---------- packed degree: one u64 atomic per edge ----------
// bits [40:63] = count, bits [0:39] = weighted degree in 2^-24 fixed point
__global__ __launch_bounds__(256) void k_deg(const void* __restrict__ ei, const float* __restrict__ w,
                                             unsigned long long* __restrict__ packed,
                                             const int* __restrict__ flag, int E) {
    int e = blockIdx.x * 256 + threadIdx.x;
    if (e >= E) return;
    int is64 = *flag;
    int c = edge_at(ei, (long long)E + e, is64);
    unsigned long long inc = (1ULL << 40) |
        (unsigned long long)(unsigned int)__float2uint_rn(w[e] * FIX_SCALE);
    atomicAdd(&packed[c], inc);
}

// ---------- packed -> deg^-1/2 ----------
__global__ __launch_bounds__(256) void k_dis(const unsigned long long* __restrict__ packed,
                                             float* __restrict__ dis, int N) {
    int i = blockIdx.x * 256 + threadIdx.x;
    if (i < N) {
        float d = (float)(packed[i] & ((1ULL << 40) - 1)) * FIX_INV;
        dis[i] = (d > 0.f) ? rsqrtf(d) : 0.f;
    }
}

// ---------- exclusive scan of packed counts -> row_start (+row_next copy) ----------
__global__ __launch_bounds__(256) void k_scan_part(const unsigned long long* __restrict__ packed,
                                                   int* __restrict__ partial, int N) {
    __shared__ int sdata[256];
    int b = blockIdx.x, t = threadIdx.x;
    int base = b * CHUNK;
    int sum = 0;
    #pragma unroll
    for (int q = 0; q < CHUNK / 256; ++q) {
        int idx = base + q * 256 + t;
        if (idx < N) sum += (int)(packed[idx] >> 40);
    }
    sdata[t] = sum; __syncthreads();
    for (int off = 128; off > 0; off >>= 1) {
        if (t < off) sdata[t] += sdata[t + off];
        __syncthreads();
    }
    if (t == 0) partial[b] = sdata[0];
}

__global__ void k_scan_top(int* partial, int nparts, int* row_start, int* row_next, int N) {
    if (blockIdx.x == 0 && threadIdx.x == 0) {
        int run = 0;
        for (int i = 0; i < nparts; ++i) { int v = partial[i]; partial[i] = run; run += v; }
        row_start[N] = run;   // == E
        row_next[N] = run;
    }
}

__global__ __launch_bounds__(256) void k_scan_chunk(const unsigned long long* __restrict__ packed,
                                                    const int* __restrict__ partial,
                                                    int* __restrict__ row_start,
                                                    int* __restrict__ row_next, int N) {
    __shared__ int tsum[256];
    __shared__ int toff[256];
    int b = blockIdx.x, t = threadIdx.x;
    int base = b * CHUNK + t * 8;
    int v[8]; int s = 0;
    #pragma unroll
    for (int q = 0; q < 8; ++q) {
        int idx = base + q;
        v[q] = (idx < N) ? (int)(packed[idx] >> 40) : 0;
        s += v[q];
    }
    tsum[t] = s; __syncthreads();
    if (t == 0) {
        int run = partial[b];
        for (int i = 0; i < 256; ++i) { int x = tsum[i]; toff[i] = run; run += x; }
    }
    __syncthreads();
    int ex = toff[t];
    #pragma unroll
    for (int q = 0; q < 8; ++q) {
        int idx = base + q;
        if (idx < N) { row_start[idx] = ex; row_next[idx] = ex; }
        ex += v[q];
    }
}

// ---------- CSR fill: csr[pos] = {src, norm} grouped by dst ----------
__global__ __launch_bounds__(256) void k_fill(const void* __restrict__ ei, const float* __restrict__ w,
                                              const float* __restrict__ dis,
                                              int* __restrict__ row_next, int2* __restrict__ csr,
                                              const int* __restrict__ flag, int E) {
    int e = blockIdx.x * 256 + threadIdx.x;
    if (e >= E) return;
    int is64 = *flag;
    int r = edge_at(ei, e, is64);
    int c = edge_at(ei, (long long)E + e, is64);
    float nm = dis[r] * w[e] * dis[c];
    int pos = atomicAdd(&row_next[c], 1);
    csr[pos] = make_int2(r, __float_as_int(nm));
}

// ---------- GEMM1: h1lin[N,64] = x[N,128] @ W1[64,128]^T ----------
__global__ __launch_bounds__(256) void k_gemm1(const float* __restrict__ x, const float* __restrict__ W1,
                                               float* __restrict__ h1lin, int N) {
    __shared__ float Wt[FIN * FHID];    // Wt[k*64+j] = W1[j*128+k]  (32 KB)
    __shared__ float xt[32 * FIN];      // 16 KB
    int t = threadIdx.x;
    for (int i = t; i < FHID * FIN; i += 256) {
        int j = i >> 7, k = i & 127;
        Wt[k * FHID + j] = W1[i];
    }
    int r0 = blockIdx.x * 32;
    const float4* xg = (const float4*)(x + (size_t)r0 * FIN);
    float4* xt4 = (float4*)xt;
    #pragma unroll
    for (int q = 0; q < 4; ++q) {
        int i = t + q * 256;            // 1024 float4 total, 32 per row
        if (r0 + (i >> 5) < N) xt4[i] = xg[i];
    }
    __syncthreads();
    int j = t & 63, rg = t >> 6;        // rg uniform per wave
    float acc[8];
    #pragma unroll
    for (int r = 0; r < 8; ++r) acc[r] = 0.f;
    for (int kk = 0; kk < FIN; kk += 4) {
        float w0 = Wt[(kk + 0) * FHID + j];
        float w1 = Wt[(kk + 1) * FHID + j];
        float w2 = Wt[(kk + 2) * FHID + j];
        float w3 = Wt[(kk + 3) * FHID + j];
        #pragma unroll
        for (int r = 0; r < 8; ++r) {
            float4 xv = xt4[(rg * 8 + r) * 32 + (kk >> 2)];
            acc[r] += xv.x * w0 + xv.y * w1 + xv.z * w2 + xv.w * w3;
        }
    }
    #pragma unroll
    for (int r = 0; r < 8; ++r) {
        int row = r0 + rg * 8 + r;
        if (row < N) h1lin[(size_t)row * FHID + j] = acc[r];
    }
}

// ---------- aggregation layer1: h1 = relu(sum norm*h1lin[src] + b1), F=64 ----------
__global__ __launch_bounds__(256) void k_agg1(const int2* __restrict__ csr, const int* __restrict__ row_start,
                                              const float* __restrict__ h1lin, const float* __restrict__ b1,
                                              float* __restrict__ h1, int N) {
    int wid = threadIdx.x >> 6, lane = threadIdx.x & 63;
    int node = blockIdx.x * 4 + wid;
    if (node >= N) return;
    int s = row_start[node], epos = row_start[node + 1];
    float acc = 0.f;
    for (int base = s; base < epos; base += 64) {
        int m = epos - base; if (m > 64) m = 64;
        int2 ent = (lane < m) ? csr[base + lane] : make_int2(0, 0);
        for (int i = 0; i < m; ++i) {
            int src = __shfl(ent.x, i);
            float nm = __shfl(__int_as_float(ent.y), i);
            acc += nm * h1lin[(size_t)src * FHID + lane];
        }
    }
    h1[(size_t)node * FHID + lane] = fmaxf(acc + b1[lane], 0.f);
}

// ---------- aggregation layer2 (pre-transform): aggv = sum norm*h1[src], F=64 ----------
__global__ __launch_bounds__(256) void k_agg2(const int2* __restrict__ csr, const int* __restrict__ row_start,
                                              const float* __restrict__ h1, float* __restrict__ aggv, int N) {
    int wid = threadIdx.x >> 6, lane = threadIdx.x & 63;
    int node = blockIdx.x * 4 + wid;
    if (node >= N) return;
    int s = row_start[node], epos = row_start[node + 1];
    float acc = 0.f;
    for (int base = s; base < epos; base += 64) {
        int m = epos - base; if (m > 64) m = 64;
        int2 ent = (lane < m) ? csr[base + lane] : make_int2(0, 0);
        for (int i = 0; i < m; ++i) {
            int src = __shfl(ent.x, i);
            float nm = __shfl(__int_as_float(ent.y), i);
            acc += nm * h1[(size_t)src * FHID + lane];
        }
    }
    aggv[(size_t)node * FHID + lane] = acc;
}

// ---------- GEMM2 fused: out[N,128] = relu(aggv[N,64] @ W2[128,64]^T + b2) ----------
__global__ __launch_bounds__(256) void k_gemm2(const float* __restrict__ A, const float* __restrict__ W2,
                                               const float* __restrict__ b2, float* __restrict__ out, int N) {
    __shared__ float Wt[FHID * FIN];    // Wt[k*128+j] = W2[j*64+k]  (32 KB)
    __shared__ float xt[16 * FHID];     // 4 KB
    int t = threadIdx.x;
    for (int i = t; i < FIN * FHID; i += 256) {
        int j = i >> 6, k = i & 63;
        Wt[k * FIN + j] = W2[i];
    }
    int r0 = blockIdx.x * 16;
    const float4* xg = (const float4*)(A + (size_t)r0 * FHID);
    float4* xt4 = (float4*)xt;
    {
        int i = t;                      // 256 float4 total, 16 per row
        if (r0 + (i >> 4) < N) xt4[i] = xg[i];
    }
    __syncthreads();
    int j = t & 127, rg = t >> 7;       // rg uniform per wave
    float acc[8];
    #pragma unroll
    for (int r = 0; r < 8; ++r) acc[r] = 0.f;
    for (int kk = 0; kk < FHID; kk += 4) {
        float w0 = Wt[(kk + 0) * FIN + j];
        float w1 = Wt[(kk + 1) * FIN + j];
        float w2 = Wt[(kk + 2) * FIN + j];
        float w3 = Wt[(kk + 3) * FIN + j];
        #pragma unroll
        for (int r = 0; r < 8; ++r) {
            float4 xv = xt4[(rg * 8 + r) * 16 + (kk >> 2)];
            acc[r] += xv.x * w0 + xv.y * w1 + xv.z * w2 + xv.w * w3;
        }
    }
    float bj = b2[j];
    #pragma unroll
    for (int r = 0; r < 8; ++r) {
        int row = r0 + rg * 8 + r;
        if (row < N) out[(size_t)row * FIN + j] = fmaxf(acc[r] + bj, 0.f);
    }
}

extern "C" void kernel_launch(void* const* d_in, const int* in_sizes, int n_in,
                              void* d_out, int out_size, void* d_ws, size_t ws_size,
                              hipStream_t stream) {
    const float* x  = (const float*)d_in[0];
    const void*  ei = d_in[1];
    const float* w  = (const float*)d_in[2];
    const float* W1 = (const float*)d_in[3];
    const float* b1 = (const float*)d_in[4];
    const float* W2 = (const float*)d_in[5];
    const float* b2 = (const float*)d_in[6];
    float* out = (float*)d_out;
    int N = in_sizes[0] / FIN;
    int E = in_sizes[2];

    char* ws = (char*)d_ws;
    size_t off = 0;
    auto alloc = [&](size_t b) { size_t o = off; off = (off + b + 255) & ~255ULL; return o; };
    int*   flag      = (int*)(ws + alloc(4));
    unsigned long long* packed = (unsigned long long*)(ws + alloc((size_t)N * 8));
    float* dis       = (float*)(ws + alloc((size_t)N * 4));
    int*   row_start = (int*)(ws + alloc((size_t)(N + 1) * 4));
    int*   row_next  = (int*)(ws + alloc((size_t)(N + 1) * 4));
    int*   partial   = (int*)(ws + alloc(4096));
    int2*  csr       = (int2*)(ws + alloc((size_t)E * 8));
    float* h1        = (float*)(ws + alloc((size_t)N * FHID * 4));
    float* scratch   = (float*)(ws + alloc((size_t)N * FHID * 4)); // h1lin, then aggv

    hipMemsetAsync(packed, 0, (size_t)N * 8, stream);

    k_detect<<<1, 64, 0, stream>>>((const uint32_t*)ei, flag);

    int eb = (E + 255) / 256;
    k_deg<<<eb, 256, 0, stream>>>(ei, w, packed, flag, E);
    k_dis<<<(N + 255) / 256, 256, 0, stream>>>(packed, dis, N);

    int nparts = (N + CHUNK - 1) / CHUNK;
    k_scan_part<<<nparts, 256, 0, stream>>>(packed, partial, N);
    k_scan_top<<<1, 64, 0, stream>>>(partial, nparts, row_start, row_next, N);
    k_scan_chunk<<<nparts, 256, 0, stream>>>(packed, partial, row_start, row_next, N);

    k_fill<<<eb, 256, 0, stream>>>(ei, w, dis, row_next, csr, flag, E);

    k_gemm1<<<(N + 31) / 32, 256, 0, stream>>>(x, W1, scratch, N);
    k_agg1<<<(N + 3) / 4, 256, 0, stream>>>(csr, row_start, scratch, b1, h1, N);
    k_agg2<<<(N + 3) / 4, 256, 0, stream>>>(csr, row_start, h1, scratch, N);
    k_gemm2<<<(N + 15) / 16, 256, 0, stream>>>(scratch, W2, b2, out, N);
}

// Round 3
// 1720.503 us; speedup vs baseline: 1.2894x; 1.1143x over previous
//
#include <hip/hip_runtime.h>
#include <stdint.h>

// x[N,128] f32, edge_index[2,E] int32/64, ew[E] f32, W1[64,128], b1[64], W2[128,64], b2[128]
#define FIN 128
#define FHID 64
#define CHUNK 2048
#define FIX_SCALE 16777216.0f   // 2^24
#define FIX_INV   (1.0f / 16777216.0f)

// ---------- dtype detection: int64 edge_index has odd 32-bit words == 0 ----------
__global__ void k_detect(const uint32_t* __restrict__ ei, int* __restrict__ flag) {
    if (blockIdx.x == 0 && threadIdx.x == 0) {
        uint32_t o = 0;
        #pragma unroll
        for (int i = 1; i < 16; i += 2) o |= ei[i];
        *flag = (o == 0) ? 1 : 0;
    }
}

__device__ __forceinline__ int edge_at(const void* ei, long long idx, int is64) {
    if (is64) return (int)((const long long*)ei)[idx];
    return ((const int*)ei)[idx];
}

// ---------- packed degree + per-edge rank: one u64 atomic per edge ----------
// bits [40:63] = count, bits [0:39] = weighted degree in 2^-24 fixed point
__global__ __launch_bounds__(256) void k_deg(const void* __restrict__ ei, const float* __restrict__ w,
                                             unsigned long long* __restrict__ packed,
                                             int* __restrict__ rank,
                                             const int* __restrict__ flag, int E) {
    int e = blockIdx.x * 256 + threadIdx.x;
    if (e >= E) return;
    int is64 = *flag;
    int c = edge_at(ei, (long long)E + e, is64);
    unsigned long long inc = (1ULL << 40) |
        (unsigned long long)(unsigned int)__float2uint_rn(w[e] * FIX_SCALE);
    unsigned long long old = atomicAdd(&packed[c], inc);
    rank[e] = (int)(old >> 40);
}

// ---------- packed -> deg^-1/2 ----------
__global__ __launch_bounds__(256) void k_dis(const unsigned long long* __restrict__ packed,
                                             float* __restrict__ dis, int N) {
    int i = blockIdx.x * 256 + threadIdx.x;
    if (i < N) {
        float d = (float)(packed[i] & ((1ULL << 40) - 1)) * FIX_INV;
        dis[i] = (d > 0.f) ? rsqrtf(d) : 0.f;
    }
}

// ---------- exclusive scan of packed counts -> row_start ----------
__global__ __launch_bounds__(256) void k_scan_part(const unsigned long long* __restrict__ packed,
                                                   int* __restrict__ partial, int N) {
    __shared__ int sdata[256];
    int b = blockIdx.x, t = threadIdx.x;
    int base = b * CHUNK;
    int sum = 0;
    #pragma unroll
    for (int q = 0; q < CHUNK / 256; ++q) {
        int idx = base + q * 256 + t;
        if (idx < N) sum += (int)(packed[idx] >> 40);
    }
    sdata[t] = sum; __syncthreads();
    for (int off = 128; off > 0; off >>= 1) {
        if (t < off) sdata[t] += sdata[t + off];
        __syncthreads();
    }
    if (t == 0) partial[b] = sdata[0];
}

__global__ void k_scan_top(int* partial, int nparts, int* row_start, int N) {
    if (blockIdx.x == 0 && threadIdx.x == 0) {
        int run = 0;
        for (int i = 0; i < nparts; ++i) { int v = partial[i]; partial[i] = run; run += v; }
        row_start[N] = run;   // == E
    }
}

__global__ __launch_bounds__(256) void k_scan_chunk(const unsigned long long* __restrict__ packed,
                                                    const int* __restrict__ partial,
                                                    int* __restrict__ row_start, int N) {
    __shared__ int tsum[256];
    __shared__ int toff[256];
    int b = blockIdx.x, t = threadIdx.x;
    int base = b * CHUNK + t * 8;
    int v[8]; int s = 0;
    #pragma unroll
    for (int q = 0; q < 8; ++q) {
        int idx = base + q;
        v[q] = (idx < N) ? (int)(packed[idx] >> 40) : 0;
        s += v[q];
    }
    tsum[t] = s; __syncthreads();
    if (t == 0) {
        int run = partial[b];
        for (int i = 0; i < 256; ++i) { int x = tsum[i]; toff[i] = run; run += x; }
    }
    __syncthreads();
    int ex = toff[t];
    #pragma unroll
    for (int q = 0; q < 8; ++q) {
        int idx = base + q;
        if (idx < N) row_start[idx] = ex;
        ex += v[q];
    }
}

// ---------- CSR fill (atomic-free): csr[row_start[c]+rank[e]] = {src, norm} ----------
__global__ __launch_bounds__(256) void k_fill(const void* __restrict__ ei, const float* __restrict__ w,
                                              const float* __restrict__ dis,
                                              const int* __restrict__ row_start,
                                              const int* __restrict__ rank,
                                              int2* __restrict__ csr,
                                              const int* __restrict__ flag, int E) {
    int e = blockIdx.x * 256 + threadIdx.x;
    if (e >= E) return;
    int is64 = *flag;
    int r = edge_at(ei, e, is64);
    int c = edge_at(ei, (long long)E + e, is64);
    float nm = dis[r] * w[e] * dis[c];
    int pos = row_start[c] + rank[e];
    csr[pos] = make_int2(r, __float_as_int(nm));
}

// ---------- GEMM1: h1lin[N,64] = x[N,128] @ W1[64,128]^T ----------
__global__ __launch_bounds__(256, 4) void k_gemm1(const float* __restrict__ x, const float* __restrict__ W1,
                                                  float* __restrict__ h1lin, int N) {
    __shared__ float Wt[FIN * 65];      // Wt[k*65+j] = W1[j*128+k], padded: conflict-free
    __shared__ float xt[32 * FIN];      // 16 KB
    int t = threadIdx.x;
    for (int i = t; i < FHID * FIN; i += 256) {
        int j = i >> 7, k = i & 127;
        Wt[k * 65 + j] = W1[i];         // lane-varying k -> stride 65 -> conflict-free
    }
    int r0 = blockIdx.x * 32;
    const float4* xg = (const float4*)(x + (size_t)r0 * FIN);
    float4* xt4 = (float4*)xt;
    #pragma unroll
    for (int q = 0; q < 4; ++q) {
        int i = t + q * 256;            // 1024 float4 total, 32 per row
        if (r0 + (i >> 5) < N) xt4[i] = xg[i];
    }
    __syncthreads();
    int j = t & 63, rg = t >> 6;        // rg uniform per wave
    float acc[8];
    #pragma unroll
    for (int r = 0; r < 8; ++r) acc[r] = 0.f;
    for (int kk = 0; kk < FIN; kk += 4) {
        float w0 = Wt[(kk + 0) * 65 + j];
        float w1 = Wt[(kk + 1) * 65 + j];
        float w2 = Wt[(kk + 2) * 65 + j];
        float w3 = Wt[(kk + 3) * 65 + j];
        #pragma unroll
        for (int r = 0; r < 8; ++r) {
            float4 xv = xt4[(rg * 8 + r) * 32 + (kk >> 2)];
            acc[r] += xv.x * w0 + xv.y * w1 + xv.z * w2 + xv.w * w3;
        }
    }
    #pragma unroll
    for (int r = 0; r < 8; ++r) {
        int row = r0 + rg * 8 + r;
        if (row < N) h1lin[(size_t)row * FHID + j] = acc[r];
    }
}

// ---------- aggregation layer1: h1 = relu(sum norm*h1lin[src] + b1), F=64 ----------
__global__ __launch_bounds__(256) void k_agg1(const int2* __restrict__ csr, const int* __restrict__ row_start,
                                              const float* __restrict__ h1lin, const float* __restrict__ b1,
                                              float* __restrict__ h1, int N) {
    int wid = threadIdx.x >> 6, lane = threadIdx.x & 63;
    int node = blockIdx.x * 4 + wid;
    if (node >= N) return;
    int s = row_start[node], epos = row_start[node + 1];
    float acc = 0.f;
    for (int base = s; base < epos; base += 64) {
        int m = epos - base; if (m > 64) m = 64;
        int2 ent = (lane < m) ? csr[base + lane] : make_int2(0, 0);
        for (int i = 0; i < m; ++i) {
            int src = __shfl(ent.x, i);
            float nm = __shfl(__int_as_float(ent.y), i);
            acc += nm * h1lin[(size_t)src * FHID + lane];
        }
    }
    h1[(size_t)node * FHID + lane] = fmaxf(acc + b1[lane], 0.f);
}

// ---------- fused agg2 + GEMM2: out = relu((sum norm*h1[src]) @ W2^T + b2) ----------
#define A2_NPB 32   // nodes per block (8 per wave)
__global__ __launch_bounds__(256) void k_agg2f(const int2* __restrict__ csr, const int* __restrict__ row_start,
                                               const float* __restrict__ h1, const float* __restrict__ W2,
                                               const float* __restrict__ b2, float* __restrict__ out, int N) {
    __shared__ float Wt[FHID * 129];    // Wt[k*129+j] = W2[j*64+k], padded: conflict-free
    int t = threadIdx.x;
    for (int i = t; i < FIN * FHID; i += 256) {
        int j = i >> 6, k = i & 63;
        Wt[k * 129 + j] = W2[i];        // lane-varying k -> stride 129 -> conflict-free
    }
    __syncthreads();
    int wid = t >> 6, lane = t & 63;
    int node0 = blockIdx.x * A2_NPB + wid * (A2_NPB / 4);
    #pragma unroll 1
    for (int q = 0; q < A2_NPB / 4; ++q) {
        int node = node0 + q;
        if (node >= N) break;
        int s = row_start[node], epos = row_start[node + 1];
        float acc = 0.f;
        for (int base = s; base < epos; base += 64) {
            int m = epos - base; if (m > 64) m = 64;
            int2 ent = (lane < m) ? csr[base + lane] : make_int2(0, 0);
            for (int i = 0; i < m; ++i) {
                int src = __shfl(ent.x, i);
                float nm = __shfl(__int_as_float(ent.y), i);
                acc += nm * h1[(size_t)src * FHID + lane];
            }
        }
        // epilogue: out[node][j] = relu(sum_k acc_k * W2[j][k] + b2[j]), j = lane, lane+64
        float o0 = b2[lane], o1 = b2[lane + 64];
        #pragma unroll 4
        for (int k = 0; k < FHID; ++k) {
            float a = __shfl(acc, k);   // uniform index -> readlane broadcast
            o0 += a * Wt[k * 129 + lane];
            o1 += a * Wt[k * 129 + 64 + lane];
        }
        out[(size_t)node * FIN + lane] = fmaxf(o0, 0.f);
        out[(size_t)node * FIN + 64 + lane] = fmaxf(o1, 0.f);
    }
}

extern "C" void kernel_launch(void* const* d_in, const int* in_sizes, int n_in,
                              void* d_out, int out_size, void* d_ws, size_t ws_size,
                              hipStream_t stream) {
    const float* x  = (const float*)d_in[0];
    const void*  ei = d_in[1];
    const float* w  = (const float*)d_in[2];
    const float* W1 = (const float*)d_in[3];
    const float* b1 = (const float*)d_in[4];
    const float* W2 = (const float*)d_in[5];
    const float* b2 = (const float*)d_in[6];
    float* out = (float*)d_out;
    int N = in_sizes[0] / FIN;
    int E = in_sizes[2];

    char* ws = (char*)d_ws;
    size_t off = 0;
    auto alloc = [&](size_t b) { size_t o = off; off = (off + b + 255) & ~255ULL; return o; };
    int*   flag      = (int*)(ws + alloc(4));
    unsigned long long* packed = (unsigned long long*)(ws + alloc((size_t)N * 8));
    float* dis       = (float*)(ws + alloc((size_t)N * 4));
    int*   row_start = (int*)(ws + alloc((size_t)(N + 1) * 4));
    int*   partial   = (int*)(ws + alloc(4096));
    int2*  csr       = (int2*)(ws + alloc((size_t)E * 8));
    float* h1        = (float*)(ws + alloc((size_t)N * FHID * 4));
    float* scratch   = (float*)(ws + alloc((size_t)N * FHID * 4)); // rank (E*4 <= N*256B), then h1lin
    int*   rank      = (int*)scratch;   // alias: rank dead before k_gemm1 writes h1lin

    hipMemsetAsync(packed, 0, (size_t)N * 8, stream);

    k_detect<<<1, 64, 0, stream>>>((const uint32_t*)ei, flag);

    int eb = (E + 255) / 256;
    k_deg<<<eb, 256, 0, stream>>>(ei, w, packed, rank, flag, E);
    k_dis<<<(N + 255) / 256, 256, 0, stream>>>(packed, dis, N);

    int nparts = (N + CHUNK - 1) / CHUNK;
    k_scan_part<<<nparts, 256, 0, stream>>>(packed, partial, N);
    k_scan_top<<<1, 64, 0, stream>>>(partial, nparts, row_start, N);
    k_scan_chunk<<<nparts, 256, 0, stream>>>(packed, partial, row_start, N);

    k_fill<<<eb, 256, 0, stream>>>(ei, w, dis, row_start, rank, csr, flag, E);

    k_gemm1<<<(N + 31) / 32, 256, 0, stream>>>(x, W1, scratch, N);
    k_agg1<<<(N + 3) / 4, 256, 0, stream>>>(csr, row_start, scratch, b1, h1, N);
    k_agg2f<<<(N + A2_NPB - 1) / A2_NPB, 256, 0, stream>>>(csr, row_start, h1, W2, b2, out, N);
}

// Round 4
// 1180.906 us; speedup vs baseline: 1.8786x; 1.4569x over previous
//
#include <hip/hip_runtime.h>
#include <stdint.h>

// x[N,128] f32, edge_index[2,E] int32/64, ew[E] f32, W1[64,128], b1[64], W2[128,64], b2[128]
#define FIN 128
#define FHID 64
#define CHUNK 2048
#define FIX_SCALE 16777216.0f   // 2^24
#define FIX_INV   (1.0f / 16777216.0f)

// ---------- dtype detection: int64 edge_index has odd 32-bit words == 0 ----------
__global__ void k_detect(const uint32_t* __restrict__ ei, int* __restrict__ flag) {
    if (blockIdx.x == 0 && threadIdx.x == 0) {
        uint32_t o = 0;
        #pragma unroll
        for (int i = 1; i < 16; i += 2) o |= ei[i];
        *flag = (o == 0) ? 1 : 0;
    }
}

__device__ __forceinline__ int edge_at(const void* ei, long long idx, int is64) {
    if (is64) return (int)((const long long*)ei)[idx];
    return ((const int*)ei)[idx];
}

// ---------- packed degree + per-edge rank: one u64 atomic per edge ----------
// bits [40:63] = count, bits [0:39] = weighted degree in 2^-24 fixed point
__global__ __launch_bounds__(256) void k_deg(const void* __restrict__ ei, const float* __restrict__ w,
                                             unsigned long long* __restrict__ packed,
                                             int* __restrict__ rank,
                                             const int* __restrict__ flag, int E) {
    int e = blockIdx.x * 256 + threadIdx.x;
    if (e >= E) return;
    int is64 = *flag;
    int c = edge_at(ei, (long long)E + e, is64);
    unsigned long long inc = (1ULL << 40) |
        (unsigned long long)(unsigned int)__float2uint_rn(w[e] * FIX_SCALE);
    unsigned long long old = atomicAdd(&packed[c], inc);
    rank[e] = (int)(old >> 40);
}

// ---------- packed -> deg^-1/2 ----------
__global__ __launch_bounds__(256) void k_dis(const unsigned long long* __restrict__ packed,
                                             float* __restrict__ dis, int N) {
    int i = blockIdx.x * 256 + threadIdx.x;
    if (i < N) {
        float d = (float)(packed[i] & ((1ULL << 40) - 1)) * FIX_INV;
        dis[i] = (d > 0.f) ? rsqrtf(d) : 0.f;
    }
}

// ---------- exclusive scan of packed counts -> row_start ----------
__global__ __launch_bounds__(256) void k_scan_part(const unsigned long long* __restrict__ packed,
                                                   int* __restrict__ partial, int N) {
    __shared__ int sdata[256];
    int b = blockIdx.x, t = threadIdx.x;
    int base = b * CHUNK;
    int sum = 0;
    #pragma unroll
    for (int q = 0; q < CHUNK / 256; ++q) {
        int idx = base + q * 256 + t;
        if (idx < N) sum += (int)(packed[idx] >> 40);
    }
    sdata[t] = sum; __syncthreads();
    for (int off = 128; off > 0; off >>= 1) {
        if (t < off) sdata[t] += sdata[t + off];
        __syncthreads();
    }
    if (t == 0) partial[b] = sdata[0];
}

__global__ void k_scan_top(int* partial, int nparts, int* row_start, int N) {
    if (blockIdx.x == 0 && threadIdx.x == 0) {
        int run = 0;
        for (int i = 0; i < nparts; ++i) { int v = partial[i]; partial[i] = run; run += v; }
        row_start[N] = run;   // == E
    }
}

__global__ __launch_bounds__(256) void k_scan_chunk(const unsigned long long* __restrict__ packed,
                                                    const int* __restrict__ partial,
                                                    int* __restrict__ row_start, int N) {
    __shared__ int tsum[256];
    __shared__ int toff[256];
    int b = blockIdx.x, t = threadIdx.x;
    int base = b * CHUNK + t * 8;
    int v[8]; int s = 0;
    #pragma unroll
    for (int q = 0; q < 8; ++q) {
        int idx = base + q;
        v[q] = (idx < N) ? (int)(packed[idx] >> 40) : 0;
        s += v[q];
    }
    tsum[t] = s; __syncthreads();
    if (t == 0) {
        int run = partial[b];
        for (int i = 0; i < 256; ++i) { int x = tsum[i]; toff[i] = run; run += x; }
    }
    __syncthreads();
    int ex = toff[t];
    #pragma unroll
    for (int q = 0; q < 8; ++q) {
        int idx = base + q;
        if (idx < N) row_start[idx] = ex;
        ex += v[q];
    }
}

// ---------- CSR fill (atomic-free): csr[row_start[c]+rank[e]] = {src, norm} ----------
__global__ __launch_bounds__(256) void k_fill(const void* __restrict__ ei, const float* __restrict__ w,
                                              const float* __restrict__ dis,
                                              const int* __restrict__ row_start,
                                              const int* __restrict__ rank,
                                              int2* __restrict__ csr,
                                              const int* __restrict__ flag, int E) {
    int e = blockIdx.x * 256 + threadIdx.x;
    if (e >= E) return;
    int is64 = *flag;
    int r = edge_at(ei, e, is64);
    int c = edge_at(ei, (long long)E + e, is64);
    float nm = dis[r] * w[e] * dis[c];
    int pos = row_start[c] + rank[e];
    csr[pos] = make_int2(r, __float_as_int(nm));
}

// ---------- W2 transpose: W2t[k*128+j] = W2[j*64+k] ----------
__global__ __launch_bounds__(256) void k_w2t(const float* __restrict__ W2, float* __restrict__ W2t) {
    int i = blockIdx.x * 256 + threadIdx.x;   // 8192 elements
    if (i < FIN * FHID) {
        int j = i >> 6, k = i & 63;
        W2t[k * FIN + j] = W2[i];
    }
}

// ---------- GEMM1: h1lin[N,64] = x[N,128] @ W1[64,128]^T ----------
__global__ __launch_bounds__(256, 4) void k_gemm1(const float* __restrict__ x, const float* __restrict__ W1,
                                                  float* __restrict__ h1lin, int N) {
    __shared__ float Wt[FIN * 65];      // Wt[k*65+j] = W1[j*128+k], padded: conflict-free
    __shared__ float xt[32 * FIN];      // 16 KB
    int t = threadIdx.x;
    for (int i = t; i < FHID * FIN; i += 256) {
        int j = i >> 7, k = i & 127;
        Wt[k * 65 + j] = W1[i];         // lane-varying k -> stride 65 -> conflict-free
    }
    int r0 = blockIdx.x * 32;
    const float4* xg = (const float4*)(x + (size_t)r0 * FIN);
    float4* xt4 = (float4*)xt;
    #pragma unroll
    for (int q = 0; q < 4; ++q) {
        int i = t + q * 256;            // 1024 float4 total, 32 per row
        if (r0 + (i >> 5) < N) xt4[i] = xg[i];
    }
    __syncthreads();
    int j = t & 63, rg = t >> 6;        // rg uniform per wave
    float acc[8];
    #pragma unroll
    for (int r = 0; r < 8; ++r) acc[r] = 0.f;
    for (int kk = 0; kk < FIN; kk += 4) {
        float w0 = Wt[(kk + 0) * 65 + j];
        float w1 = Wt[(kk + 1) * 65 + j];
        float w2 = Wt[(kk + 2) * 65 + j];
        float w3 = Wt[(kk + 3) * 65 + j];
        #pragma unroll
        for (int r = 0; r < 8; ++r) {
            float4 xv = xt4[(rg * 8 + r) * 32 + (kk >> 2)];
            acc[r] += xv.x * w0 + xv.y * w1 + xv.z * w2 + xv.w * w3;
        }
    }
    #pragma unroll
    for (int r = 0; r < 8; ++r) {
        int row = r0 + rg * 8 + r;
        if (row < N) h1lin[(size_t)row * FHID + j] = acc[r];
    }
}

// ---------- gather-accumulate one node's row: 4 independent chains ----------
__device__ __forceinline__ float agg_row(const int2* __restrict__ csr, int s, int epos,
                                         const float* __restrict__ tab, int lane) {
    float a0 = 0.f, a1 = 0.f, a2 = 0.f, a3 = 0.f;
    for (int base = s; base < epos; base += 64) {
        int m = epos - base; if (m > 64) m = 64;
        int2 ent = (lane < m) ? csr[base + lane] : make_int2(0, 0);
        int i = 0;
        for (; i + 4 <= m; i += 4) {
            int   s0 = __shfl(ent.x, i + 0); float n0 = __shfl(__int_as_float(ent.y), i + 0);
            int   s1 = __shfl(ent.x, i + 1); float n1 = __shfl(__int_as_float(ent.y), i + 1);
            int   s2 = __shfl(ent.x, i + 2); float n2 = __shfl(__int_as_float(ent.y), i + 2);
            int   s3 = __shfl(ent.x, i + 3); float n3 = __shfl(__int_as_float(ent.y), i + 3);
            float v0 = tab[(size_t)((unsigned)s0 << 6) + lane];
            float v1 = tab[(size_t)((unsigned)s1 << 6) + lane];
            float v2 = tab[(size_t)((unsigned)s2 << 6) + lane];
            float v3 = tab[(size_t)((unsigned)s3 << 6) + lane];
            a0 += n0 * v0; a1 += n1 * v1; a2 += n2 * v2; a3 += n3 * v3;
        }
        for (; i < m; ++i) {
            int   s0 = __shfl(ent.x, i); float n0 = __shfl(__int_as_float(ent.y), i);
            a0 += n0 * tab[(size_t)((unsigned)s0 << 6) + lane];
        }
    }
    return (a0 + a1) + (a2 + a3);
}

// ---------- aggregation layer1: h1 = relu(sum norm*h1lin[src] + b1), F=64 ----------
__global__ __launch_bounds__(256) void k_agg1(const int2* __restrict__ csr, const int* __restrict__ row_start,
                                              const float* __restrict__ h1lin, const float* __restrict__ b1,
                                              float* __restrict__ h1, int N) {
    int wid = threadIdx.x >> 6, lane = threadIdx.x & 63;
    int node = blockIdx.x * 4 + wid;
    if (node >= N) return;
    float acc = agg_row(csr, row_start[node], row_start[node + 1], h1lin, lane);
    h1[(size_t)node * FHID + lane] = fmaxf(acc + b1[lane], 0.f);
}

// ---------- fused agg2 + GEMM2 (no LDS): out = relu((sum norm*h1[src]) @ W2t + b2) ----------
__global__ __launch_bounds__(256) void k_agg2f(const int2* __restrict__ csr, const int* __restrict__ row_start,
                                               const float* __restrict__ h1, const float* __restrict__ W2t,
                                               const float* __restrict__ b2, float* __restrict__ out, int N) {
    int wid = threadIdx.x >> 6, lane = threadIdx.x & 63;
    int node = blockIdx.x * 4 + wid;
    if (node >= N) return;
    float acc = agg_row(csr, row_start[node], row_start[node + 1], h1, lane);
    // epilogue: out[node][j] = relu(sum_k acc_k * W2t[k][j] + b2[j]), j = lane, lane+64
    float o0 = b2[lane], o1 = b2[lane + 64];
    #pragma unroll 4
    for (int k = 0; k < FHID; ++k) {
        float a = __shfl(acc, k);       // uniform index -> broadcast
        o0 += a * W2t[k * FIN + lane];          // coalesced 256B, L1-resident
        o1 += a * W2t[k * FIN + 64 + lane];
    }
    out[(size_t)node * FIN + lane] = fmaxf(o0, 0.f);
    out[(size_t)node * FIN + 64 + lane] = fmaxf(o1, 0.f);
}

extern "C" void kernel_launch(void* const* d_in, const int* in_sizes, int n_in,
                              void* d_out, int out_size, void* d_ws, size_t ws_size,
                              hipStream_t stream) {
    const float* x  = (const float*)d_in[0];
    const void*  ei = d_in[1];
    const float* w  = (const float*)d_in[2];
    const float* W1 = (const float*)d_in[3];
    const float* b1 = (const float*)d_in[4];
    const float* W2 = (const float*)d_in[5];
    const float* b2 = (const float*)d_in[6];
    float* out = (float*)d_out;
    int N = in_sizes[0] / FIN;
    int E = in_sizes[2];

    char* ws = (char*)d_ws;
    size_t off = 0;
    auto alloc = [&](size_t b) { size_t o = off; off = (off + b + 255) & ~255ULL; return o; };
    int*   flag      = (int*)(ws + alloc(4));
    unsigned long long* packed = (unsigned long long*)(ws + alloc((size_t)N * 8));
    float* dis       = (float*)(ws + alloc((size_t)N * 4));
    int*   row_start = (int*)(ws + alloc((size_t)(N + 1) * 4));
    int*   partial   = (int*)(ws + alloc(4096));
    float* W2t       = (float*)(ws + alloc((size_t)FIN * FHID * 4));
    int2*  csr       = (int2*)(ws + alloc((size_t)E * 8));
    float* h1        = (float*)(ws + alloc((size_t)N * FHID * 4));
    float* scratch   = (float*)(ws + alloc((size_t)N * FHID * 4)); // rank (E*4 <= N*256B), then h1lin
    int*   rank      = (int*)scratch;   // alias: rank dead before k_gemm1 writes h1lin

    hipMemsetAsync(packed, 0, (size_t)N * 8, stream);

    k_detect<<<1, 64, 0, stream>>>((const uint32_t*)ei, flag);

    int eb = (E + 255) / 256;
    k_deg<<<eb, 256, 0, stream>>>(ei, w, packed, rank, flag, E);
    k_dis<<<(N + 255) / 256, 256, 0, stream>>>(packed, dis, N);

    int nparts = (N + CHUNK - 1) / CHUNK;
    k_scan_part<<<nparts, 256, 0, stream>>>(packed, partial, N);
    k_scan_top<<<1, 64, 0, stream>>>(partial, nparts, row_start, N);
    k_scan_chunk<<<nparts, 256, 0, stream>>>(packed, partial, row_start, N);

    k_fill<<<eb, 256, 0, stream>>>(ei, w, dis, row_start, rank, csr, flag, E);
    k_w2t<<<(FIN * FHID + 255) / 256, 256, 0, stream>>>(W2, W2t);

    k_gemm1<<<(N + 31) / 32, 256, 0, stream>>>(x, W1, scratch, N);
    k_agg1<<<(N + 3) / 4, 256, 0, stream>>>(csr, row_start, scratch, b1, h1, N);
    k_agg2f<<<(N + 3) / 4, 256, 0, stream>>>(csr, row_start, h1, W2t, b2, out, N);
}